// Round 10
// baseline (225.588 us; speedup 1.0000x reference)
//
#include <hip/hip_runtime.h>
#include <stdint.h>

typedef __bf16 bf16_t;
typedef __bf16 bf16x4 __attribute__((ext_vector_type(4)));
typedef __bf16 bf16x8 __attribute__((ext_vector_type(8)));
typedef float  f32x4  __attribute__((ext_vector_type(4)));

#define AS1 __attribute__((address_space(1)))
#define AS3 __attribute__((address_space(3)))

__device__ __forceinline__ void gld_lds16(const bf16_t* g, void* s) {
  // async global->LDS, 16 bytes per lane; HW dest = wave-uniform base + lane*16
  __builtin_amdgcn_global_load_lds((const AS1 uint32_t*)g, (AS3 uint32_t*)s, 16, 0, 0);
}

// ---------------------------------------------------------------------------
// 0) fp32 -> bf16 canonicalization, all 4 tensors in ONE dispatch.
// ---------------------------------------------------------------------------
__global__ __launch_bounds__(256) void convert_all_kernel(
    const float* __restrict__ X,  const float* __restrict__ Wq,
    const float* __restrict__ Wk, const float* __restrict__ Wv,
    bf16_t* __restrict__ Xc, bf16_t* __restrict__ Wqc,
    bf16_t* __restrict__ Wkc, bf16_t* __restrict__ Wvc) {
  const int blk = blockIdx.x;
  const float* src; bf16_t* dst; int base;
  if (blk < 4096)      { src = X;  dst = Xc;  base = 0;    }
  else if (blk < 4608) { src = Wq; dst = Wqc; base = 4096; }
  else if (blk < 5120) { src = Wk; dst = Wkc; base = 4608; }
  else                 { src = Wv; dst = Wvc; base = 5120; }
  const int i = ((blk - base) * 256 + threadIdx.x) * 8;
  const float4 a = ((const float4*)(src + i))[0];
  const float4 b = ((const float4*)(src + i))[1];
  bf16x8 v;
  v[0] = (bf16_t)a.x; v[1] = (bf16_t)a.y; v[2] = (bf16_t)a.z; v[3] = (bf16_t)a.w;
  v[4] = (bf16_t)b.x; v[5] = (bf16_t)b.y; v[6] = (bf16_t)b.z; v[7] = (bf16_t)b.w;
  *(bf16x8*)(dst + i) = v;
}

// ---------------------------------------------------------------------------
// THIN core: 128x256 tile, BK=32, 8 waves (512 thr), wave grid 2M x 4N,
// per-wave 64x64 = acc[4][4]. Double-buffered: As 2x8KB + Bs 2x16KB = 48 KB.
// Counted vmcnt(3); swizzle slot = ck^((row>>1)&3) (R9-verified ~0 conflict).
// ---------------------------------------------------------------------------
__device__ __forceinline__ void gemm_thin_core(
    const bf16_t* __restrict__ A, int lda,
    const bf16_t* __restrict__ B, int ldb,
    int m0, int n0, int kEnd,
    char* lds, f32x4 acc[4][4])
{
  const int tid  = threadIdx.x;
  const int lane = tid & 63;
  const int wave = tid >> 6;           // 0..7
  const int wm = (wave >> 2) * 64;     // 0 / 64
  const int wn = (wave & 3) * 64;      // 0 / 64 / 128 / 192
  const int fr = lane & 15;
  const int ck = lane >> 4;            // 16B chunk of the 32-k slice

  const int srow = tid >> 2;           // 0..127
  const int sch  = tid & 3;
  const int kg   = (sch ^ ((srow >> 1) & 3)) * 8;  // inverse-swizzled k off
  const int dstA = srow * 64 + sch * 16;
  const int dstB = dstA;

  const bf16_t* Ar  = A + (size_t)(m0 + srow) * lda + kg;
  const bf16_t* Br0 = B + (size_t)(n0 + srow) * ldb + kg;
  const bf16_t* Br1 = B + (size_t)(n0 + srow + 128) * ldb + kg;

  int aoff[4], boff[4];
#pragma unroll
  for (int i = 0; i < 4; ++i) {
    const int ra = wm + i * 16 + fr;           // 0..127
    const int rb = wn + i * 16 + fr;           // 0..255
    aoff[i] = ra * 64 + ((ck ^ ((ra >> 1) & 3)) * 16);
    boff[i] = rb * 64 + ((ck ^ ((rb >> 1) & 3)) * 16);
  }

  gld_lds16(Ar, lds + dstA);
  gld_lds16(Br0, lds + 16384 + dstB);
  gld_lds16(Br1, lds + 16384 + 8192 + dstB);

  const int NK = kEnd >> 5;
  int cur = 0;
  for (int t = 0; t < NK; ++t) {
    const int nxt = cur ^ 1;
    if (t + 1 < NK) {
      const int ko = (t + 1) * 32;
      gld_lds16(Ar + ko, lds + nxt * 8192 + dstA);
      gld_lds16(Br0 + ko, lds + 16384 + nxt * 16384 + dstB);
      gld_lds16(Br1 + ko, lds + 16384 + nxt * 16384 + 8192 + dstB);
      asm volatile("s_waitcnt vmcnt(3)" ::: "memory");
    } else {
      asm volatile("s_waitcnt vmcnt(0)" ::: "memory");
    }
    __builtin_amdgcn_sched_barrier(0);
    __builtin_amdgcn_s_barrier();
    __builtin_amdgcn_sched_barrier(0);

    const char* Ab = lds + cur * 8192;
    const char* Bb = lds + 16384 + cur * 16384;
    bf16x8 af[4], bfv[4];
#pragma unroll
    for (int i = 0; i < 4; ++i) {
      af[i]  = *(const bf16x8*)(Ab + aoff[i]);
      bfv[i] = *(const bf16x8*)(Bb + boff[i]);
    }
    asm volatile("s_waitcnt lgkmcnt(0)" ::: "memory");
    __builtin_amdgcn_sched_barrier(0);
    __builtin_amdgcn_s_setprio(1);
#pragma unroll
    for (int mi = 0; mi < 4; ++mi)
#pragma unroll
      for (int ni = 0; ni < 4; ++ni)
        acc[mi][ni] = __builtin_amdgcn_mfma_f32_16x16x32_bf16(
            af[mi], bfv[ni], acc[mi][ni], 0, 0, 0);
    __builtin_amdgcn_s_setprio(0);
    __builtin_amdgcn_sched_barrier(0);
    __builtin_amdgcn_s_barrier();
    __builtin_amdgcn_sched_barrier(0);
    cur = nxt;
  }
}

// ---------------------------------------------------------------------------
// 128x128 4-wave core (R6 counted-vmcnt) -- pv.
// ---------------------------------------------------------------------------
__device__ __forceinline__ void gemm_bt_core(
    const bf16_t* __restrict__ A, int lda,
    const bf16_t* __restrict__ B, int ldb,
    int m0, int n0, int kBeg, int kEnd,
    bf16_t* As, bf16_t* Bs, f32x4 acc[4][4])
{
  const int lane = threadIdx.x & 63;
  const int wave = threadIdx.x >> 6;
  const int wm = (wave >> 1) * 64;
  const int wn = (wave & 1) * 64;
  const int fr = lane & 15;
  const int ck = lane >> 4;

  const int off0 = wave * 2048 + lane * 16;
  const int row0 = wave * 32 + (lane >> 2);
  const int row1 = row0 + 16;
  const int kg   = ((lane & 3) ^ ((row0 >> 1) & 3)) * 8;

  const bf16_t* Ar0 = A + (size_t)(m0 + row0) * lda + kg;
  const bf16_t* Ar1 = A + (size_t)(m0 + row1) * lda + kg;
  const bf16_t* Br0 = B + (size_t)(n0 + row0) * ldb + kg;
  const bf16_t* Br1 = B + (size_t)(n0 + row1) * ldb + kg;

  int aoff[4], boff[4];
#pragma unroll
  for (int i = 0; i < 4; ++i) {
    const int ra = wm + i * 16 + fr;
    const int rb = wn + i * 16 + fr;
    aoff[i] = ra * 64 + ((ck ^ ((ra >> 1) & 3)) * 16);
    boff[i] = rb * 64 + ((ck ^ ((rb >> 1) & 3)) * 16);
  }

  gld_lds16(Ar0 + kBeg, (char*)As + off0);
  gld_lds16(Ar1 + kBeg, (char*)As + off0 + 1024);
  gld_lds16(Br0 + kBeg, (char*)Bs + off0);
  gld_lds16(Br1 + kBeg, (char*)Bs + off0 + 1024);

  int cur = 0;
  for (int kt = kBeg; kt < kEnd; kt += 32) {
    const int nxt = cur ^ 1;
    if (kt + 32 < kEnd) {
      gld_lds16(Ar0 + kt + 32, (char*)As + nxt * 8192 + off0);
      gld_lds16(Ar1 + kt + 32, (char*)As + nxt * 8192 + off0 + 1024);
      gld_lds16(Br0 + kt + 32, (char*)Bs + nxt * 8192 + off0);
      gld_lds16(Br1 + kt + 32, (char*)Bs + nxt * 8192 + off0 + 1024);
      asm volatile("s_waitcnt vmcnt(4)" ::: "memory");
    } else {
      asm volatile("s_waitcnt vmcnt(0)" ::: "memory");
    }
    __builtin_amdgcn_sched_barrier(0);
    __builtin_amdgcn_s_barrier();
    __builtin_amdgcn_sched_barrier(0);

    bf16x8 af[4], bfv[4];
#pragma unroll
    for (int mi = 0; mi < 4; ++mi)
      af[mi] = *(const bf16x8*)((char*)As + cur * 8192 + aoff[mi]);
#pragma unroll
    for (int ni = 0; ni < 4; ++ni)
      bfv[ni] = *(const bf16x8*)((char*)Bs + cur * 8192 + boff[ni]);
    __builtin_amdgcn_s_setprio(1);
#pragma unroll
    for (int mi = 0; mi < 4; ++mi)
#pragma unroll
      for (int ni = 0; ni < 4; ++ni)
        acc[mi][ni] = __builtin_amdgcn_mfma_f32_16x16x32_bf16(
            af[mi], bfv[ni], acc[mi][ni], 0, 0, 0);
    __builtin_amdgcn_s_setprio(0);

    asm volatile("s_waitcnt lgkmcnt(0)" ::: "memory");
    __builtin_amdgcn_sched_barrier(0);
    __builtin_amdgcn_s_barrier();
    __builtin_amdgcn_sched_barrier(0);
    cur = nxt;
  }
}

// ---------------------------------------------------------------------------
// 1) QKV, thin tiles. 768 uniform 128x256 blocks = exactly 3 rounds; 48KB
// LDS -> 2-3 blocks/CU co-residency. z==2 writes Vt[b][d][s] directly.
// ---------------------------------------------------------------------------
__global__ __launch_bounds__(512) void qkv_kernel(
    const bf16_t* __restrict__ X,
    const bf16_t* __restrict__ Wq, const bf16_t* __restrict__ Wk,
    const bf16_t* __restrict__ Wv,
    bf16_t* __restrict__ Q, bf16_t* __restrict__ K, bf16_t* __restrict__ Vt)
{
  __shared__ bf16_t smem[24576];             // 48 KB
  const int bid = blockIdx.x;
  const int z   = bid >> 8;
  const int t   = bid & 255;
  const int m0  = (t >> 2) * 128;
  const int n0  = (t & 3) * 256;
  const bf16_t* W = (z == 0) ? Wq : (z == 1) ? Wk : Wv;

  f32x4 acc[4][4] = {};
  gemm_thin_core(X, 1024, W, 1024, m0, n0, 1024, (char*)smem, acc);

  const int tid  = threadIdx.x;
  const int lane = tid & 63;
  const int wave = tid >> 6;
  const int wm = (wave >> 2) * 64, wn = (wave & 3) * 64;

  if (z < 2) {
    bf16_t* Out = z ? K : Q;
#pragma unroll
    for (int mi = 0; mi < 4; ++mi)
#pragma unroll
      for (int r = 0; r < 4; ++r) {
        const int row = m0 + wm + mi * 16 + (lane >> 4) * 4 + r;
#pragma unroll
        for (int ni = 0; ni < 4; ++ni) {
          const int col = n0 + wn + ni * 16 + (lane & 15);
          Out[(size_t)row * 1024 + col] = (bf16_t)acc[mi][ni][r];
        }
      }
  } else {
    const int b  = m0 >> 11;
    const int s0 = m0 & 2047;
    bf16_t* Vtb = Vt + (size_t)b * 1024 * 2048;
    bf16_t (*tb)[136] = (bf16_t(*)[136])smem;  // 64*136*2 = 17.4 KB
#pragma unroll
    for (int h = 0; h < 4; ++h) {              // d-quarter rounds
      __syncthreads();
      if ((wave & 3) == h) {
#pragma unroll
        for (int mi = 0; mi < 4; ++mi)
#pragma unroll
          for (int ni = 0; ni < 4; ++ni) {
            const int c    = ni * 16 + (lane & 15);
            const int rowl = wm + mi * 16 + (lane >> 4) * 4;
            bf16x4 v;
            v[0] = (bf16_t)acc[mi][ni][0]; v[1] = (bf16_t)acc[mi][ni][1];
            v[2] = (bf16_t)acc[mi][ni][2]; v[3] = (bf16_t)acc[mi][ni][3];
            *(bf16x4*)&tb[c][rowl] = v;
          }
      }
      __syncthreads();
#pragma unroll
      for (int i = 0; i < 2; ++i) {
        const int idx = tid + 512 * i;         // 0..1023
        const int d   = idx >> 4;              // 0..63
        const int ch  = idx & 15;
        bf16x8 vv = *(const bf16x8*)&tb[d][ch * 8];
        *(bf16x8*)(Vtb + (size_t)(n0 + h * 64 + d) * 2048 + s0 + ch * 8) = vv;
      }
    }
  }
}

// ---------------------------------------------------------------------------
// 3) Fused scores+exp, thin 128q x 256k causal tiles. R10: COMPACT 288-block
// grid, XCD-colored by mt-PAIR. XCD = L%8 (linear round-robin): color c
// hosts mts {c, 15-c}; per color per batch exactly 9 uniform full-K tiles
// ((c>>1)+1 for mt=c, ((15-c)>>1)+1 for mt=15-c) -> every XCD gets 36 equal
// blocks AND its Q working set (2 mts x 4z x 0.25MB = 2MB) is L2-resident.
// Also removes the 224 early-exit dispatch slots of the old (8,16,4) grid.
// ---------------------------------------------------------------------------
__global__ __launch_bounds__(512) void scores_exp_kernel(
    const bf16_t* __restrict__ Q, const bf16_t* __restrict__ K,
    bf16_t* __restrict__ P, float* __restrict__ partials)
{
  const int L = blockIdx.x;           // 0..287
  const int c   = L & 7;              // XCD color = mt-pair
  const int idx = L >> 3;             // 0..35
  const int batch = idx / 9;
  const int r     = idx % 9;
  const int lo    = (c >> 1) + 1;     // tiles of mt=c
  int mt, nt;
  if (r < lo) { mt = c;      nt = r; }
  else        { mt = 15 - c; nt = r - lo; }
  const int m0 = mt * 128;
  const int n0 = nt * 256;
  __shared__ bf16_t smem[24576];      // 48 KB (core dbuf; reused for rowsum)
  const bf16_t* Qb = Q + (size_t)batch * 2048 * 1024;
  const bf16_t* Kb = K + (size_t)batch * 2048 * 1024;
  bf16_t* Pb = P + (size_t)batch * 2048 * 2048;
  float* lp  = partials + (size_t)batch * 16 * 2048;

  f32x4 acc[4][4] = {};
  gemm_thin_core(Qb, 1024, Kb, 1024, m0, n0, 1024, (char*)smem, acc);

  const int tid  = threadIdx.x;
  const int lane = tid & 63;
  const int wave = tid >> 6;
  const int wm = (wave >> 2) * 64, wn = (wave & 3) * 64;
  float (*rs4)[128] = (float(*)[128])smem;   // 4 col-quarters x 128 rows
  const float cst = 0.04508422f;      // log2(e)/32
#pragma unroll
  for (int mi = 0; mi < 4; ++mi)
#pragma unroll
    for (int rr = 0; rr < 4; ++rr) {
      const int lrow = wm + mi * 16 + (lane >> 4) * 4 + rr;  // 0..127
      const int row  = m0 + lrow;
      float rs = 0.f;
#pragma unroll
      for (int ni = 0; ni < 4; ++ni) {
        const int col = n0 + wn + ni * 16 + (lane & 15);
        float p = exp2f(acc[mi][ni][rr] * cst);
        if (col > row) p = 0.f;
        const bf16_t pb = (bf16_t)p;
        Pb[(size_t)row * 2048 + col] = pb;
        rs += (float)pb;              // sum the rounded value pv reads
      }
      rs += __shfl_xor(rs, 1);
      rs += __shfl_xor(rs, 2);
      rs += __shfl_xor(rs, 4);
      rs += __shfl_xor(rs, 8);
      if ((lane & 15) == 0) rs4[wave & 3][lrow] = rs;  // col-quarter partial
    }
  __syncthreads();
  if (tid < 256) {
    const int row = tid & 127;
    const int s   = tid >> 7;         // 0..1 -> 128-k slice within 256 tile
    lp[(size_t)(2 * nt + s) * 2048 + m0 + row] =
        rs4[2 * s][row] + rs4[2 * s + 1][row];
  }
}

// ---------------------------------------------------------------------------
// 3.5) Row-sum finalize: Linv[z][row] = 1 / sum_{kt<=row>>7} lp[z][kt][row].
// ---------------------------------------------------------------------------
__global__ __launch_bounds__(256) void lsum_kernel(
    const float* __restrict__ partials, float* __restrict__ Linv)
{
  const int id  = blockIdx.x * 256 + threadIdx.x;  // z*2048 + row
  const int z   = id >> 11;
  const int row = id & 2047;
  const float* lp = partials + (size_t)z * 16 * 2048;
  const int tmax = row >> 7;
  float l = 0.f;
  for (int kt = 0; kt <= tmax; ++kt) l += lp[kt * 2048 + row];
  Linv[id] = 1.f / l;
}

// ---------------------------------------------------------------------------
// 4) PV, 128x128 GEMM, R10 XCD-colored grid. L in [0,512):
//   c = L&7 (XCD color = mt-pair), s = (L>>3)&31 -> z = s&3, dt = s>>2,
//   hi = L>>8, mt = hi ? 15-c : c.
// All 64 blocks reading the P-pair {mt=c,15-c} land on ONE XCD (P set
// ~2.2MB < 4MB L2: fetched once per XCD instead of 8x from HBM). Co-resident
// pair (L, L+256) differs only in hi -> per-CU work = (c+1)+(16-c) = 17
// k128-tiles exactly. Causality: kEnd = m0+128.
// ---------------------------------------------------------------------------
__global__ __launch_bounds__(256) void pv_kernel(
    const bf16_t* __restrict__ P, const bf16_t* __restrict__ Vt,
    const float* __restrict__ Linv, float* __restrict__ out)
{
  __shared__ bf16_t smem[4 * 128 * 32];
  bf16_t* As = smem;
  bf16_t* Bs = smem + 2 * 128 * 32;
  const int L  = blockIdx.x;
  const int c  = L & 7;
  const int s  = (L >> 3) & 31;
  const int hi = L >> 8;
  const int zb = s & 3;
  const int dt = s >> 2;                       // 0..7
  const int mt = hi ? (15 - c) : c;
  const int m0 = mt * 128;
  const int n0 = dt * 128;                     // d
  const bf16_t* Pb  = P  + (size_t)zb * 2048 * 2048;
  const bf16_t* Vtb = Vt + (size_t)zb * 1024 * 2048;
  const float* li = Linv + (size_t)zb * 2048;
  float* ob = out + (size_t)zb * 2048 * 1024;

  f32x4 acc[4][4] = {};
  gemm_bt_core(Pb, 2048, Vtb, 2048, m0, n0, 0, m0 + 128, As, Bs, acc);

  const int lane = threadIdx.x & 63;
  const int wave = threadIdx.x >> 6;
  const int wm = (wave >> 1) * 64, wn = (wave & 1) * 64;
#pragma unroll
  for (int mi = 0; mi < 4; ++mi)
#pragma unroll
    for (int r = 0; r < 4; ++r) {
      const int row = m0 + wm + mi * 16 + (lane >> 4) * 4 + r;
      const float inv = li[row];
#pragma unroll
      for (int ni = 0; ni < 4; ++ni) {
        const int col = n0 + wn + ni * 16 + (lane & 15);
        ob[(size_t)row * 1024 + col] = acc[mi][ni][r] * inv;
      }
    }
}

// ---------------------------------------------------------------------------
// R10 workspace (identical layout):
//   [0,16M) Q | [16,32M) K | [32,48M) Vt | [48,80M) P (aliases Xc+W)
//   [80,80.5M) Lp | [80.5M,..) Linv
// Order: convert -> qkv(768) -> scores(288 compact) -> lsum -> pv(512).
// ---------------------------------------------------------------------------
extern "C" void kernel_launch(void* const* d_in, const int* in_sizes, int n_in,
                              void* d_out, int out_size, void* d_ws, size_t ws_size,
                              hipStream_t stream) {
  const float* X  = (const float*)d_in[0];
  const float* Wq = (const float*)d_in[1];
  const float* Wk = (const float*)d_in[2];
  const float* Wv = (const float*)d_in[3];
  float* out = (float*)d_out;
  char* ws = (char*)d_ws;

  const size_t MB = 1024 * 1024;
  bf16_t* Q    = (bf16_t*)(ws + 0 * MB);
  bf16_t* K    = (bf16_t*)(ws + 16 * MB);
  bf16_t* Vt   = (bf16_t*)(ws + 32 * MB);
  bf16_t* Xc   = (bf16_t*)(ws + 48 * MB);
  bf16_t* Wqc  = (bf16_t*)(ws + 64 * MB);
  bf16_t* Wkc  = (bf16_t*)(ws + 66 * MB);
  bf16_t* Wvc  = (bf16_t*)(ws + 68 * MB);
  bf16_t* P    = (bf16_t*)(ws + 48 * MB);   // aliases Xc+W, extends to 80M
  float*  Lp   = (float*)(ws + 80 * MB);
  float*  Linv = (float*)(ws + 80 * MB + 512 * 1024);

  convert_all_kernel<<<dim3(5632), 256, 0, stream>>>(X, Wq, Wk, Wv, Xc, Wqc, Wkc, Wvc);
  qkv_kernel<<<dim3(768), 512, 0, stream>>>(Xc, Wqc, Wkc, Wvc, Q, K, Vt);
  scores_exp_kernel<<<dim3(288), 512, 0, stream>>>(Q, K, P, Lp);
  lsum_kernel<<<dim3(32), 256, 0, stream>>>(Lp, Linv);
  pv_kernel<<<dim3(512), 256, 0, stream>>>(P, Vt, Linv, out);
}